// Round 5
// baseline (1665.762 us; speedup 1.0000x reference)
//
#include <hip/hip_runtime.h>

// Fused GRU (Keras reset_after=True, relu) for MI355X — round 5.
// Key change vs r4: recurrence uses v_readlane h-broadcast (register-only
// steps, NO LDS, NO sync inside a step), and the grid is one-pass:
//   grid = 256 blocks (2 batch rows each) x 4 waves = 1024 waves = 1/SIMD.
//   wave0: rec row0   wave1: rec row1   (different SIMDs)
//   wave2: x-proj row0  wave3: x-proj row1 (bf16x3 MFMA, W streamed from L2,
//          double-buffered Xb, ONE __syncthreads per 16-step chunk)
// VGPR: rec wave holds U f32-resident (192 regs) -> 1 wave/SIMD, intended.

#define B_SZ   512
#define T_SZ   512
#define F_SZ   128
#define UN     64
#define G3     192
#define CHUNK  16
#define NCHUNK (T_SZ / CHUNK)
#define NCLS   10
#define XPAD   193

using short8 = __attribute__((ext_vector_type(8))) short;
using f32x4  = __attribute__((ext_vector_type(4))) float;

__device__ __forceinline__ unsigned short f2bf_rn(float f) {
    unsigned int u = __float_as_uint(f);
    unsigned int r = u + 0x7FFFu + ((u >> 16) & 1u);
    return (unsigned short)(r >> 16);
}
__device__ __forceinline__ float bf2f(unsigned short s) {
    return __uint_as_float(((unsigned int)s) << 16);
}
__device__ __forceinline__ float sigmoidf_(float x) {
    return 1.0f / (1.0f + __expf(-x));
}
__device__ __forceinline__ float rdlane(float v, int l) {
    return __uint_as_float(__builtin_amdgcn_readlane(__float_as_uint(v), l));
}
// ordering fence for same-wave LDS write->read (cross-lane) in the epilogue
#define WAVE_SYNC() asm volatile("s_waitcnt lgkmcnt(0)" ::: "memory")

__global__ __launch_bounds__(256, 1)
void gru_fused5(const float* __restrict__ inp,   // [512,512,128]
                const float* __restrict__ W,     // [128,192]
                const float* __restrict__ U,     // [64,192]
                const float* __restrict__ bias,  // [2,192]
                const float* __restrict__ W1,    // [64,64]
                const float* __restrict__ b1,    // [64]
                const float* __restrict__ W2,    // [64,10]
                const float* __restrict__ b2,    // [10]
                float* __restrict__ out)         // [512,10]
{
    const int tid   = threadIdx.x;
    const int wave  = tid >> 6;
    const int lane  = tid & 63;
    const int l15   = lane & 15;
    const int l4    = lane >> 4;
    const int myrow = wave & 1;
    const int row   = blockIdx.x * 2 + myrow;

    __shared__ __align__(16) float Xb[2][2][CHUNK][XPAD]; // [buf][row][t][192] ~49.4KB
    __shared__ float hb[2][UN];
    __shared__ float sc[2][UN];
    __shared__ float lg[2][NCLS];

    if (wave >= 2) {
        // ======================= producer =======================
        float b0c[12];
        #pragma unroll
        for (int t = 0; t < 12; ++t) b0c[t] = bias[16 * t + l15];
        const float* arow = inp + (size_t)row * T_SZ * F_SZ;

        auto stage = [&](int cc) {
            const int buf = cc & 1;
            f32x4 acc[12];
            #pragma unroll
            for (int t = 0; t < 12; ++t) acc[t] = (f32x4){0.f, 0.f, 0.f, 0.f};
            #pragma unroll
            for (int kt = 0; kt < 4; ++kt) {
                // A fragment: row(t)=l15, k = 32*kt + 8*l4 + e
                const float* ap = arow + (size_t)(cc * CHUNK + l15) * F_SZ + 32 * kt + 8 * l4;
                f32x4 v0 = *(const f32x4*)(ap);
                f32x4 v1 = *(const f32x4*)(ap + 4);
                float av[8] = {v0[0], v0[1], v0[2], v0[3], v1[0], v1[1], v1[2], v1[3]};
                short8 ah8, al8;
                #pragma unroll
                for (int e = 0; e < 8; ++e) {
                    unsigned short hi = f2bf_rn(av[e]);
                    unsigned short lo = f2bf_rn(av[e] - bf2f(hi));
                    ah8[e] = (short)hi; al8[e] = (short)lo;
                }
                #pragma unroll
                for (int t = 0; t < 12; ++t) {
                    // B fragment streamed from L2 (W is 98KB, cache-resident)
                    short8 wh, wl;
                    #pragma unroll
                    for (int e = 0; e < 8; ++e) {
                        float w = W[(size_t)(32 * kt + 8 * l4 + e) * G3 + 16 * t + l15];
                        unsigned short hi = f2bf_rn(w);
                        unsigned short lo = f2bf_rn(w - bf2f(hi));
                        wh[e] = (short)hi; wl[e] = (short)lo;
                    }
                    acc[t] = __builtin_amdgcn_mfma_f32_16x16x32_bf16(ah8, wh, acc[t], 0, 0, 0);
                    acc[t] = __builtin_amdgcn_mfma_f32_16x16x32_bf16(al8, wh, acc[t], 0, 0, 0);
                    acc[t] = __builtin_amdgcn_mfma_f32_16x16x32_bf16(ah8, wl, acc[t], 0, 0, 0);
                }
            }
            // D layout: col = l15 (tile col), row = 4*l4 + q
            #pragma unroll
            for (int t = 0; t < 12; ++t) {
                #pragma unroll
                for (int q = 0; q < 4; ++q)
                    Xb[buf][myrow][4 * l4 + q][16 * t + l15] = acc[t][q] + b0c[t];
            }
        };

        stage(0);
        __syncthreads();
        for (int c = 0; c < NCHUNK; ++c) {
            if (c + 1 < NCHUNK) stage(c + 1);
            __syncthreads();
        }
        // producers done; rec waves run their own epilogue (no more barriers)
    } else {
        // ======================= recurrence =======================
        // lane j owns unit j; U columns register-resident (192 VGPR)
        float uzc[UN], urc[UN], uhc[UN];
        #pragma unroll
        for (int k = 0; k < UN; ++k) {
            uzc[k] = U[(size_t)k * G3 + lane];
            urc[k] = U[(size_t)k * G3 + 64 + lane];
            uhc[k] = U[(size_t)k * G3 + 128 + lane];
        }
        const float brz = bias[G3 + lane];
        const float brr = bias[G3 + 64 + lane];
        const float brh = bias[G3 + 128 + lane];
        float h = 0.f;

        __syncthreads();

        for (int c = 0; c < NCHUNK; ++c) {
            const int buf = c & 1;
            for (int s = 0; s < CHUNK; ++s) {
                const float xz = Xb[buf][myrow][s][lane];
                const float xr = Xb[buf][myrow][s][64 + lane];
                const float xh = Xb[buf][myrow][s][128 + lane];

                // register-only h broadcast: readlane -> SGPR, fma v,s,v,v
                float a0 = 0.f, a1 = 0.f, r0 = 0.f, r1 = 0.f, c0 = 0.f, c1 = 0.f;
                #pragma unroll
                for (int k = 0; k < UN; k += 2) {
                    const float h0 = rdlane(h, k);
                    const float h1 = rdlane(h, k + 1);
                    a0 = fmaf(h0, uzc[k],     a0);
                    r0 = fmaf(h0, urc[k],     r0);
                    c0 = fmaf(h0, uhc[k],     c0);
                    a1 = fmaf(h1, uzc[k + 1], a1);
                    r1 = fmaf(h1, urc[k + 1], r1);
                    c1 = fmaf(h1, uhc[k + 1], c1);
                }
                const float rz = a0 + a1 + brz;
                const float rr = r0 + r1 + brr;
                const float rh = c0 + c1 + brh;
                const float z  = sigmoidf_(xz + rz);
                const float rg = sigmoidf_(xr + rr);
                const float hh = fmaxf(fmaf(rg, rh, xh), 0.f);
                h = fmaf(z, h - hh, hh);
            }
            __syncthreads();
        }

        // ---------------- epilogue: head + softmax (per rec wave) ----------------
        hb[myrow][lane] = h;
        WAVE_SYNC();

        float a = b1[lane];
        #pragma unroll 8
        for (int k = 0; k < UN; ++k)
            a = fmaf(hb[myrow][k], W1[k * UN + lane], a);
        sc[myrow][lane] = fmaxf(a, 0.f);
        WAVE_SYNC();

        if (lane < NCLS) {
            float acc = b2[lane];
            #pragma unroll 8
            for (int k = 0; k < UN; ++k)
                acc = fmaf(sc[myrow][k], W2[k * NCLS + lane], acc);
            lg[myrow][lane] = acc;
        }
        WAVE_SYNC();
        if (lane < NCLS) {
            float m = lg[myrow][0];
            #pragma unroll
            for (int k = 1; k < NCLS; ++k) m = fmaxf(m, lg[myrow][k]);
            float ssum = 0.f;
            #pragma unroll
            for (int k = 0; k < NCLS; ++k) ssum += __expf(lg[myrow][k] - m);
            out[row * NCLS + lane] = __expf(lg[myrow][lane] - m) / ssum;
        }
    }
}

extern "C" void kernel_launch(void* const* d_in, const int* in_sizes, int n_in,
                              void* d_out, int out_size, void* d_ws, size_t ws_size,
                              hipStream_t stream) {
    const float* inp  = (const float*)d_in[0];
    const float* W    = (const float*)d_in[1];
    const float* U    = (const float*)d_in[2];
    const float* bias = (const float*)d_in[3];
    const float* W1   = (const float*)d_in[4];
    const float* b1   = (const float*)d_in[5];
    const float* W2   = (const float*)d_in[6];
    const float* b2   = (const float*)d_in[7];
    float* out = (float*)d_out;

    gru_fused5<<<B_SZ / 2, 256, 0, stream>>>(inp, W, U, bias, W1, b1, W2, b2, out);
}

// Round 6
// 493.943 us; speedup vs baseline: 3.3724x; 3.3724x over previous
//
#include <hip/hip_runtime.h>

// Fused GRU (Keras reset_after=True, relu) for MI355X — round 6.
// NEW: the recurrence itself is MFMA-batched. Block = 256 thr (4 waves),
// owns NB=2 batch rows. Per step (all 4 waves, 1 barrier/step):
//   rec = U^T[192x64] @ h[64 x N16(2 used)] via bf16x3 MFMA.
//   Wave w owns gate-tiles {w, w+4, w+8} (z,r,hh for units 16w..16w+15):
//   A-frags (U^T) register-resident; B-frag (h) read from LDS as packed
//   hi|lo bf16 u32 (4 ds_read_b128 + v_perm unpack); D = (batch=col, gates).
//   Gate math: 4 units/lane, h kept in registers, h packed to hx[parity^1].
// x-proj: per 8-step chunk, same waves compute X[16 rows][192] = A@W + b0
//   (W register-resident hi/lo, 36 MFMA/wave) into double-buffered Xb.
//   Gate reads touch only the OWN wave's Xb columns -> no extra barrier.
// Epilogue: wave 0 computes MLP head + softmax for both rows.

#define B_SZ 512
#define T_SZ 512
#define F_SZ 128
#define UN   64
#define G3   192
#define NB   2
#define CH   8
#define NCH  (T_SZ / CH)
#define NCLS 10
#define GP   196   // padded gate row (floats), 784B, 16B-aligned
#define UP   68    // padded unit row (u32), 272B, 16B-aligned

using short8 = __attribute__((ext_vector_type(8))) short;
using f32x4  = __attribute__((ext_vector_type(4))) float;
typedef unsigned int u32;

union S8 { short8 s; u32 u[4]; };

__device__ __forceinline__ u32 permb(u32 a, u32 b, u32 sel) {
    return __builtin_amdgcn_perm(a, b, sel);
}
__device__ __forceinline__ unsigned short f2bf_rn(float f) {
    u32 u = __float_as_uint(f);
    u32 r = u + 0x7FFFu + ((u >> 16) & 1u);
    return (unsigned short)(r >> 16);
}
__device__ __forceinline__ float bf2f(unsigned short s) {
    return __uint_as_float(((u32)s) << 16);
}
__device__ __forceinline__ float sigmoidf_(float x) {
    return 1.0f / (1.0f + __expf(-x));
}
// split pair of floats into packed-bf16 hi / lo u32 (truncation split)
__device__ __forceinline__ void split_pair(float f0, float f1, u32 &hi, u32 &lo) {
    u32 u0 = __float_as_uint(f0) & 0xffff0000u;
    u32 u1 = __float_as_uint(f1) & 0xffff0000u;
    float l0 = f0 - __uint_as_float(u0);
    float l1 = f1 - __uint_as_float(u1);
    hi = permb(u1, u0, 0x07060302u);
    lo = permb(__float_as_uint(l1), __float_as_uint(l0), 0x07060302u);
}
#define WAVE_SYNC() asm volatile("s_waitcnt lgkmcnt(0)" ::: "memory")
#define MFMA16(A, B, C) __builtin_amdgcn_mfma_f32_16x16x32_bf16((A), (B), (C), 0, 0, 0)

__global__ __launch_bounds__(256)
void gru_fused6(const float* __restrict__ inp,   // [512,512,128]
                const float* __restrict__ W,     // [128,192]
                const float* __restrict__ U,     // [64,192]
                const float* __restrict__ bias,  // [2,192]
                const float* __restrict__ W1,    // [64,64]
                const float* __restrict__ b1,    // [64]
                const float* __restrict__ W2,    // [64,10]
                const float* __restrict__ b2,    // [10]
                float* __restrict__ out)         // [512,10]
{
    const int tid  = threadIdx.x;
    const int wv   = tid >> 6;
    const int lane = tid & 63;
    const int l15  = lane & 15;
    const int l4   = lane >> 4;
    const int r0   = blockIdx.x * NB;
    const int bb   = l15 & 1;          // batch this lane's MFMA column maps to

    __shared__ __align__(16) float Xb[2][CH][NB][GP];   // ~50.2 KB
    __shared__ __align__(16) u32   hx[2][NB][UP];       // packed hi|lo h
    __shared__ __align__(16) float hfin[NB][UN];
    __shared__ float scb[NB][UN];
    __shared__ float lgb[NB][NCLS];

    // ---------------- persistent register fragments ----------------
    short8 Wh[3][4], Wl[3][4];   // x-proj B-frags: N-tiles {wv,wv+4,wv+8} x kt
    float  b0c[3];
    short8 Uh[3][2], Ul[3][2];   // rec A-frags (U^T): M-tiles {wv,wv+4,wv+8} x kc
    float  brz[4], brr[4], brh[4];
    float  hq[4] = {0.f, 0.f, 0.f, 0.f};   // h for units 16wv+4l4+q, batch bb

    #pragma unroll
    for (int nt = 0; nt < 3; ++nt) {
        const int col = 16 * (wv + 4 * nt) + l15;
        b0c[nt] = bias[col];
        #pragma unroll
        for (int kt = 0; kt < 4; ++kt) {
            #pragma unroll
            for (int e = 0; e < 8; ++e) {
                float w = W[(size_t)(32 * kt + 8 * l4 + e) * G3 + col];
                unsigned short hi = f2bf_rn(w);
                Wh[nt][kt][e] = (short)hi;
                Wl[nt][kt][e] = (short)f2bf_rn(w - bf2f(hi));
            }
        }
    }
    #pragma unroll
    for (int mt = 0; mt < 3; ++mt) {
        const int g = 16 * (wv + 4 * mt) + l15;     // gate row of U^T
        #pragma unroll
        for (int kc = 0; kc < 2; ++kc) {
            #pragma unroll
            for (int e = 0; e < 8; ++e) {
                float u = U[(size_t)(32 * kc + 8 * l4 + e) * G3 + g];
                unsigned short hi = f2bf_rn(u);
                Uh[mt][kc][e] = (short)hi;
                Ul[mt][kc][e] = (short)f2bf_rn(u - bf2f(hi));
            }
        }
    }
    #pragma unroll
    for (int q = 0; q < 4; ++q) {
        const int u = 16 * wv + 4 * l4 + q;
        brz[q] = bias[G3 + u];
        brr[q] = bias[G3 + 64 + u];
        brh[q] = bias[G3 + 128 + u];
    }
    if (tid < NB * UN) hx[0][tid >> 6][tid & 63] = 0u;

    // ---------------- x-projection producer (per chunk) ----------------
    const float* arow = inp + (size_t)(r0 + bb) * T_SZ * F_SZ
                            + (size_t)(l15 >> 1) * F_SZ;   // M-row l15 = 2t+b

    auto produce = [&](int cn) {
        const int bn = cn & 1;
        const float* ap = arow + (size_t)cn * CH * F_SZ + 8 * l4;
        f32x4 xa[3] = {{0,0,0,0},{0,0,0,0},{0,0,0,0}};
        #pragma unroll
        for (int kt = 0; kt < 4; ++kt) {
            f32x4 v0 = *(const f32x4*)(ap + 32 * kt);
            f32x4 v1 = *(const f32x4*)(ap + 32 * kt + 4);
            S8 Ah, Al;
            split_pair(v0[0], v0[1], Ah.u[0], Al.u[0]);
            split_pair(v0[2], v0[3], Ah.u[1], Al.u[1]);
            split_pair(v1[0], v1[1], Ah.u[2], Al.u[2]);
            split_pair(v1[2], v1[3], Ah.u[3], Al.u[3]);
            #pragma unroll
            for (int nt = 0; nt < 3; ++nt) {
                xa[nt] = MFMA16(Ah.s, Wh[nt][kt], xa[nt]);
                xa[nt] = MFMA16(Al.s, Wh[nt][kt], xa[nt]);
                xa[nt] = MFMA16(Ah.s, Wl[nt][kt], xa[nt]);
            }
        }
        #pragma unroll
        for (int nt = 0; nt < 3; ++nt) {
            const int col = 16 * (wv + 4 * nt) + l15;
            #pragma unroll
            for (int q = 0; q < 4; ++q) {
                const int r = 4 * l4 + q;                   // M-row = 2t+b
                Xb[bn][r >> 1][r & 1][col] = xa[nt][q] + b0c[nt];
            }
        }
    };

    __syncthreads();
    produce(0);
    __syncthreads();

    // ---------------- main loop: 64 chunks x 8 steps ----------------
    int gs = 0;
    for (int c = 0; c < NCH; ++c) {
        if (c + 1 < NCH) produce(c + 1);
        const int buf = c & 1;
        for (int s = 0; s < CH; ++s, ++gs) {
            const int p = gs & 1;
            // ---- B-frag: h packed hi|lo from LDS ----
            const u32* hrow = &hx[p][bb][0];
            uint4 a0 = *(const uint4*)&hrow[8 * l4];
            uint4 a1 = *(const uint4*)&hrow[8 * l4 + 4];
            uint4 c0 = *(const uint4*)&hrow[32 + 8 * l4];
            uint4 c1 = *(const uint4*)&hrow[32 + 8 * l4 + 4];
            S8 Hh0, Hl0, Hh1, Hl1;
            Hh0.u[0] = permb(a0.y, a0.x, 0x07060302u); Hl0.u[0] = permb(a0.y, a0.x, 0x05040100u);
            Hh0.u[1] = permb(a0.w, a0.z, 0x07060302u); Hl0.u[1] = permb(a0.w, a0.z, 0x05040100u);
            Hh0.u[2] = permb(a1.y, a1.x, 0x07060302u); Hl0.u[2] = permb(a1.y, a1.x, 0x05040100u);
            Hh0.u[3] = permb(a1.w, a1.z, 0x07060302u); Hl0.u[3] = permb(a1.w, a1.z, 0x05040100u);
            Hh1.u[0] = permb(c0.y, c0.x, 0x07060302u); Hl1.u[0] = permb(c0.y, c0.x, 0x05040100u);
            Hh1.u[1] = permb(c0.w, c0.z, 0x07060302u); Hl1.u[1] = permb(c0.w, c0.z, 0x05040100u);
            Hh1.u[2] = permb(c1.y, c1.x, 0x07060302u); Hl1.u[2] = permb(c1.y, c1.x, 0x05040100u);
            Hh1.u[3] = permb(c1.w, c1.z, 0x07060302u); Hl1.u[3] = permb(c1.w, c1.z, 0x05040100u);

            // ---- rec MFMA: 3 gate-tiles x 2 kc x bf16x3 ----
            f32x4 az = {0,0,0,0}, ar4 = {0,0,0,0}, ac4 = {0,0,0,0};
            az  = MFMA16(Uh[0][0], Hh0.s, az);  az  = MFMA16(Ul[0][0], Hh0.s, az);
            az  = MFMA16(Uh[0][0], Hl0.s, az);  az  = MFMA16(Uh[0][1], Hh1.s, az);
            az  = MFMA16(Ul[0][1], Hh1.s, az);  az  = MFMA16(Uh[0][1], Hl1.s, az);
            ar4 = MFMA16(Uh[1][0], Hh0.s, ar4); ar4 = MFMA16(Ul[1][0], Hh0.s, ar4);
            ar4 = MFMA16(Uh[1][0], Hl0.s, ar4); ar4 = MFMA16(Uh[1][1], Hh1.s, ar4);
            ar4 = MFMA16(Ul[1][1], Hh1.s, ar4); ar4 = MFMA16(Uh[1][1], Hl1.s, ar4);
            ac4 = MFMA16(Uh[2][0], Hh0.s, ac4); ac4 = MFMA16(Ul[2][0], Hh0.s, ac4);
            ac4 = MFMA16(Uh[2][0], Hl0.s, ac4); ac4 = MFMA16(Uh[2][1], Hh1.s, ac4);
            ac4 = MFMA16(Ul[2][1], Hh1.s, ac4); ac4 = MFMA16(Uh[2][1], Hl1.s, ac4);

            // ---- gates (4 units per lane) ----
            const float* xr_ = &Xb[buf][s][bb][0];
            #pragma unroll
            for (int q = 0; q < 4; ++q) {
                const int u = 16 * wv + 4 * l4 + q;
                const float xz = xr_[u], xrr = xr_[64 + u], xh = xr_[128 + u];
                const float z  = sigmoidf_(xz + az[q] + brz[q]);
                const float r  = sigmoidf_(xrr + ar4[q] + brr[q]);
                const float hh = fmaxf(fmaf(r, ac4[q] + brh[q], xh), 0.f);
                const float hn = fmaf(z, hq[q] - hh, hh);
                hq[q] = hn;
                const u32 uh_ = __float_as_uint(hn) & 0xffff0000u;
                const float lo = hn - __uint_as_float(uh_);
                const u32 pk = permb(uh_, __float_as_uint(lo), 0x07060302u);
                if (l15 < NB) hx[p ^ 1][l15][u] = pk;
            }
            __syncthreads();
        }
    }

    // ---------------- epilogue: head + softmax ----------------
    if (l15 < NB) {
        #pragma unroll
        for (int q = 0; q < 4; ++q) hfin[l15][16 * wv + 4 * l4 + q] = hq[q];
    }
    __syncthreads();

    if (wv == 0) {
        #pragma unroll
        for (int b = 0; b < NB; ++b) {
            float a = b1[lane];
            #pragma unroll 8
            for (int k = 0; k < UN; ++k)
                a = fmaf(hfin[b][k], W1[k * UN + lane], a);
            scb[b][lane] = fmaxf(a, 0.f);
        }
        WAVE_SYNC();
        if (lane < NB * NCLS) {
            const int b = lane / NCLS, cl = lane % NCLS;
            float a = b2[cl];
            #pragma unroll 8
            for (int k = 0; k < UN; ++k)
                a = fmaf(scb[b][k], W2[k * NCLS + cl], a);
            lgb[b][cl] = a;
        }
        WAVE_SYNC();
        if (lane < NB * NCLS) {
            const int b = lane / NCLS, cl = lane % NCLS;
            float m = lgb[b][0];
            #pragma unroll
            for (int k = 1; k < NCLS; ++k) m = fmaxf(m, lgb[b][k]);
            float ss = 0.f;
            #pragma unroll
            for (int k = 0; k < NCLS; ++k) ss += __expf(lgb[b][k] - m);
            out[(r0 + b) * NCLS + cl] = __expf(lgb[b][cl] - m) / ss;
        }
    }
}

extern "C" void kernel_launch(void* const* d_in, const int* in_sizes, int n_in,
                              void* d_out, int out_size, void* d_ws, size_t ws_size,
                              hipStream_t stream) {
    const float* inp  = (const float*)d_in[0];
    const float* W    = (const float*)d_in[1];
    const float* U    = (const float*)d_in[2];
    const float* bias = (const float*)d_in[3];
    const float* W1   = (const float*)d_in[4];
    const float* b1   = (const float*)d_in[5];
    const float* W2   = (const float*)d_in[6];
    const float* b2   = (const float*)d_in[7];
    float* out = (float*)d_out;

    gru_fused6<<<B_SZ / NB, 256, 0, stream>>>(inp, W, U, bias, W1, b1, W2, b2, out);
}

// Round 7
// 242.597 us; speedup vs baseline: 6.8664x; 2.0361x over previous
//
#include <hip/hip_runtime.h>

// Fused GRU (Keras reset_after=True, relu) for MI355X — round 7.
// Block = 256 thr (4 waves) = 2 batch rows. Grid = 256 = 1 block/CU, one pass.
//   Wave 0/1: recurrence for row 0/1 — REGISTER-ONLY steps: U columns f32 in
//             192 VGPR, h broadcast via v_readlane (no LDS, no barrier in-step),
//             x gates read from LDS (3 ds_read_b32/step).
//   Wave 2/3: x-proj producers, each owns 6 gate col-tiles for BOTH rows:
//             X[16][cols] = inp_chunk @ W + b0 via bf16x3 MFMA, W frags
//             register-resident (192 VGPR), double-buffered Xb.
// ONE __syncthreads per 16-step chunk (33 barriers total).
// Epilogue: each rec wave runs its own row's MLP head + softmax.

#define B_SZ   512
#define T_SZ   512
#define F_SZ   128
#define UN     64
#define G3     192
#define CHUNK  16
#define NCHUNK (T_SZ / CHUNK)
#define NCLS   10
#define GP     196   // padded gate row (floats)

using short8 = __attribute__((ext_vector_type(8))) short;
using f32x4  = __attribute__((ext_vector_type(4))) float;
typedef unsigned int u32;

union S8 { short8 s; u32 u[4]; };

__device__ __forceinline__ u32 permb(u32 a, u32 b, u32 sel) {
    return __builtin_amdgcn_perm(a, b, sel);
}
__device__ __forceinline__ unsigned short f2bf_rn(float f) {
    u32 u = __float_as_uint(f);
    u32 r = u + 0x7FFFu + ((u >> 16) & 1u);
    return (unsigned short)(r >> 16);
}
__device__ __forceinline__ float bf2f(unsigned short s) {
    return __uint_as_float(((u32)s) << 16);
}
__device__ __forceinline__ float sigmoidf_(float x) {
    return 1.0f / (1.0f + __expf(-x));
}
// pack 2 floats -> (hi-bf16 pair, lo-bf16 pair), element order [f0,f1]
__device__ __forceinline__ void split_pair(float f0, float f1, u32 &hi, u32 &lo) {
    u32 u0 = __float_as_uint(f0) & 0xffff0000u;
    u32 u1 = __float_as_uint(f1) & 0xffff0000u;
    float l0 = f0 - __uint_as_float(u0);
    float l1 = f1 - __uint_as_float(u1);
    hi = permb(u1, u0, 0x07060302u);
    lo = permb(__float_as_uint(l1), __float_as_uint(l0), 0x07060302u);
}
__device__ __forceinline__ float rdlane(float v, int l) {
    return __uint_as_float(__builtin_amdgcn_readlane(__float_as_uint(v), l));
}
#define WAVE_SYNC() asm volatile("s_waitcnt lgkmcnt(0)" ::: "memory")
#define MFMA16(A, B, C) __builtin_amdgcn_mfma_f32_16x16x32_bf16((A), (B), (C), 0, 0, 0)

__global__ __launch_bounds__(256, 1)
void gru_fused7(const float* __restrict__ inp,   // [512,512,128]
                const float* __restrict__ W,     // [128,192]
                const float* __restrict__ U,     // [64,192]
                const float* __restrict__ bias,  // [2,192]
                const float* __restrict__ W1,    // [64,64]
                const float* __restrict__ b1,    // [64]
                const float* __restrict__ W2,    // [64,10]
                const float* __restrict__ b2,    // [10]
                float* __restrict__ out)         // [512,10]
{
    const int tid  = threadIdx.x;
    const int wv   = tid >> 6;
    const int lane = tid & 63;
    const int l15  = lane & 15;
    const int l4   = lane >> 4;
    const int r0   = blockIdx.x * 2;

    __shared__ __align__(16) float Xb[2][2][CHUNK][GP];   // [buf][row][t][192] ~50.2KB
    __shared__ float hb[2][UN];
    __shared__ float sc[2][UN];
    __shared__ float lg[2][NCLS];

    if (wv >= 2) {
        // ======================= producers =======================
        const int tb = 6 * (wv - 2);      // global tile base: 0 or 6
        short8 Wh[6][4], Wl[6][4];
        float  b0c[6];
        #pragma unroll
        for (int nt = 0; nt < 6; ++nt) {
            const int col = 16 * (tb + nt) + l15;
            b0c[nt] = bias[col];
            #pragma unroll
            for (int kt = 0; kt < 4; ++kt) {
                #pragma unroll
                for (int e = 0; e < 8; ++e) {
                    float w = W[(size_t)(32 * kt + 8 * l4 + e) * G3 + col];
                    unsigned short hi = f2bf_rn(w);
                    Wh[nt][kt][e] = (short)hi;
                    Wl[nt][kt][e] = (short)f2bf_rn(w - bf2f(hi));
                }
            }
        }

        auto produce = [&](int cn) {
            const int bn = cn & 1;
            #pragma unroll
            for (int r = 0; r < 2; ++r) {
                const float* ap = inp + (size_t)(r0 + r) * T_SZ * F_SZ
                                + (size_t)(cn * CHUNK + l15) * F_SZ + 8 * l4;
                f32x4 acc[6];
                #pragma unroll
                for (int nt = 0; nt < 6; ++nt) acc[nt] = (f32x4){0.f, 0.f, 0.f, 0.f};
                #pragma unroll
                for (int kt = 0; kt < 4; ++kt) {
                    f32x4 v0 = *(const f32x4*)(ap + 32 * kt);
                    f32x4 v1 = *(const f32x4*)(ap + 32 * kt + 4);
                    S8 Ah, Al;
                    split_pair(v0[0], v0[1], Ah.u[0], Al.u[0]);
                    split_pair(v0[2], v0[3], Ah.u[1], Al.u[1]);
                    split_pair(v1[0], v1[1], Ah.u[2], Al.u[2]);
                    split_pair(v1[2], v1[3], Ah.u[3], Al.u[3]);
                    #pragma unroll
                    for (int nt = 0; nt < 6; ++nt) {
                        acc[nt] = MFMA16(Ah.s, Wh[nt][kt], acc[nt]);
                        acc[nt] = MFMA16(Al.s, Wh[nt][kt], acc[nt]);
                        acc[nt] = MFMA16(Ah.s, Wl[nt][kt], acc[nt]);
                    }
                }
                #pragma unroll
                for (int nt = 0; nt < 6; ++nt) {
                    const int col = 16 * (tb + nt) + l15;
                    #pragma unroll
                    for (int q = 0; q < 4; ++q)
                        Xb[bn][r][4 * l4 + q][col] = acc[nt][q] + b0c[nt];
                }
            }
        };

        produce(0);
        __syncthreads();
        for (int c = 0; c < NCHUNK; ++c) {
            if (c + 1 < NCHUNK) produce(c + 1);
            __syncthreads();
        }
        // done; rec waves handle epilogue
    } else {
        // ======================= recurrence (row = wv) =======================
        float uzc[UN], urc[UN], uhc[UN];
        #pragma unroll
        for (int k = 0; k < UN; ++k) {
            uzc[k] = U[(size_t)k * G3 + lane];
            urc[k] = U[(size_t)k * G3 + 64 + lane];
            uhc[k] = U[(size_t)k * G3 + 128 + lane];
        }
        const float brz = bias[G3 + lane];
        const float brr = bias[G3 + 64 + lane];
        const float brh = bias[G3 + 128 + lane];
        float h = 0.f;

        __syncthreads();

        for (int c = 0; c < NCHUNK; ++c) {
            const int buf = c & 1;
            for (int s = 0; s < CHUNK; ++s) {
                const float xz = Xb[buf][wv][s][lane];
                const float xr = Xb[buf][wv][s][64 + lane];
                const float xh = Xb[buf][wv][s][128 + lane];

                float a0 = 0.f, a1 = 0.f, r0_ = 0.f, r1_ = 0.f, c0 = 0.f, c1 = 0.f;
                #pragma unroll
                for (int k = 0; k < UN; k += 2) {
                    const float h0 = rdlane(h, k);
                    const float h1 = rdlane(h, k + 1);
                    a0  = fmaf(h0, uzc[k],     a0);
                    r0_ = fmaf(h0, urc[k],     r0_);
                    c0  = fmaf(h0, uhc[k],     c0);
                    a1  = fmaf(h1, uzc[k + 1], a1);
                    r1_ = fmaf(h1, urc[k + 1], r1_);
                    c1  = fmaf(h1, uhc[k + 1], c1);
                }
                const float rz = a0 + a1 + brz;
                const float rr = r0_ + r1_ + brr;
                const float rh = c0 + c1 + brh;
                const float z  = sigmoidf_(xz + rz);
                const float rg = sigmoidf_(xr + rr);
                const float hh = fmaxf(fmaf(rg, rh, xh), 0.f);
                h = fmaf(z, h - hh, hh);
            }
            __syncthreads();
        }

        // ---------------- epilogue: head + softmax (own row) ----------------
        hb[wv][lane] = h;
        WAVE_SYNC();

        float a = b1[lane];
        #pragma unroll 8
        for (int k = 0; k < UN; ++k)
            a = fmaf(hb[wv][k], W1[k * UN + lane], a);
        sc[wv][lane] = fmaxf(a, 0.f);
        WAVE_SYNC();

        if (lane < NCLS) {
            float acc = b2[lane];
            #pragma unroll 8
            for (int k = 0; k < UN; ++k)
                acc = fmaf(sc[wv][k], W2[k * NCLS + lane], acc);
            lg[wv][lane] = acc;
        }
        WAVE_SYNC();
        if (lane < NCLS) {
            float m = lg[wv][0];
            #pragma unroll
            for (int k = 1; k < NCLS; ++k) m = fmaxf(m, lg[wv][k]);
            float ss = 0.f;
            #pragma unroll
            for (int k = 0; k < NCLS; ++k) ss += __expf(lg[wv][k] - m);
            out[(r0 + wv) * NCLS + lane] = __expf(lg[wv][lane] - m) / ss;
        }
    }
}

extern "C" void kernel_launch(void* const* d_in, const int* in_sizes, int n_in,
                              void* d_out, int out_size, void* d_ws, size_t ws_size,
                              hipStream_t stream) {
    const float* inp  = (const float*)d_in[0];
    const float* W    = (const float*)d_in[1];
    const float* U    = (const float*)d_in[2];
    const float* bias = (const float*)d_in[3];
    const float* W1   = (const float*)d_in[4];
    const float* b1   = (const float*)d_in[5];
    const float* W2   = (const float*)d_in[6];
    const float* b2   = (const float*)d_in[7];
    float* out = (float*)d_out;

    gru_fused7<<<B_SZ / 2, 256, 0, stream>>>(inp, W, U, bias, W1, b1, W2, b2, out);
}